// Round 20
// baseline (238.824 us; speedup 1.0000x reference)
//
#include <hip/hip_runtime.h>
#include <hip/hip_cooperative_groups.h>
#include <stdint.h>

// B=8, C=128, N=4096 (64x64), GROUPS=8 (16 ch/group)
// R26: SINGLE cooperative kernel (256 blocks x 512 thr = 1 block/CU, exactly
//      co-resident). The persistent ~83us non-attn gap resisted every k_qkv
//      optimization; budget says ~40-50us of it is inter-dispatch overhead.
//      Merge all 3 kernels with grid.sync():
//        P1: GN partial sums (wave w == group w; slotted, no atomics)
//            + weight bf16 conv (64 float4/block).        grid.sync()
//        P2: stats -> h (R25-verbatim) -> Q GEMM (R25-verbatim, -> K0/K1)
//            + K GEMM -> k_ws + V GEMM -> V0/V1 -> coalesced v_ws.
//            h computed ONCE feeds Q,K,V (i-slice == n-slice).  grid.sync()
//        P3: R25 main loop + epilogues, byte-identical.
//      grid.sync() provides the device-scope release/acquire the 3-kernel
//      pipeline got from dispatch boundaries (G16).

namespace cg = cooperative_groups;

typedef __attribute__((ext_vector_type(8))) short short8;
typedef __attribute__((ext_vector_type(4))) float f32x4;
typedef __attribute__((ext_vector_type(16))) float f32x16;

#define MFMA_BF16(a, b, c) __builtin_amdgcn_mfma_f32_16x16x32_bf16((a), (b), (c), 0, 0, 0)
#define MFMA32(a, b, c) __builtin_amdgcn_mfma_f32_32x32x16_bf16((a), (b), (c), 0, 0, 0)
#define EXP2(x) __builtin_amdgcn_exp2f(x)

// (1/sqrt(128)) * log2(e) — folded into Q at store time (softmax runs in base 2)
#define QSCALE 0.12751743f

__device__ __forceinline__ unsigned short f2bf(float f) {
    unsigned int u = __builtin_bit_cast(unsigned int, f);
    u += 0x7FFFu + ((u >> 16) & 1u);   // RNE (finite values only)
    return (unsigned short)(u >> 16);
}
__device__ __forceinline__ short8 ldg8(const unsigned short* p) {
    return __builtin_bit_cast(short8, *(const uint4*)p);
}
__device__ __forceinline__ unsigned int cvtpk(float lo, float hi) {
    unsigned int r;
    asm("v_cvt_pk_bf16_f32 %0, %1, %2" : "=v"(r) : "v"(lo), "v"(hi));
    return r;
}
__device__ __forceinline__ void gload16(const void* g, void* l) {
    __builtin_amdgcn_global_load_lds(
        (__attribute__((address_space(1))) void*)g,
        (__attribute__((address_space(3))) void*)l, 16, 0, 0);
}

// ---------------- THE kernel: GN + QKV + flash attention + proj + residual --------
__global__ __launch_bounds__(512, 2) void k_fused(const float* __restrict__ x,
                                                  float* __restrict__ sums,
                                                  const float* __restrict__ qkv_w_raw,
                                                  const float* __restrict__ proj_w_raw,
                                                  unsigned short* __restrict__ wq,
                                                  unsigned short* __restrict__ wp,
                                                  const float* __restrict__ gn_w,
                                                  const float* __restrict__ gn_b,
                                                  const float* __restrict__ qkv_b,
                                                  unsigned short* __restrict__ k_ws,
                                                  unsigned short* __restrict__ v_ws,
                                                  const float* __restrict__ proj_b,
                                                  float* __restrict__ out) {
    __shared__ unsigned short K0[64][128];      // 16 KB (P2: Q rows 0..63)
    __shared__ unsigned short K1[64][128];      // 16 KB (P2: Q rows 64..127)
    __shared__ unsigned short V0[128][64];      // 16 KB (P2: vstage c 0..63)
    __shared__ unsigned short V1[128][64];      // 16 KB (P2: vstage c 64..127)
    __shared__ unsigned short O_lds[128][136];  // 34 KB (P2: h; epilogue: O)
    __shared__ float Lp[256];                   // 1 KB
    __shared__ float ms[8][2];                  // 64 B   -> ~100 KiB total

    const int tid   = threadIdx.x;              // 0..511
    const int b     = blockIdx.x & 7;           // batch -> same XCD for same b
    const int tile  = blockIdx.x >> 3;          // 0..31
    const int i0    = tile << 7;                // this block's 128-row i-slice
    const int lane  = tid & 63, wave = tid >> 6;
    const int ih    = wave >> 1, jh = wave & 1;
    const int l31   = lane & 31, h = lane >> 5;
    const int irow  = ih * 32 + l31;
    const int l15   = lane & 15, q4 = lane >> 4;

    cg::grid_group grid = cg::this_grid();

    // ================= Phase 1: GN partial sums + weight conversion =================
    if (tid < 64) {                    // weight conv: 64 float4 per block
        int i = (blockIdx.x * 64 + tid) * 4;
        const float* src; unsigned short* dst; int off;
        if (i < 49152) { src = qkv_w_raw; dst = wq; off = i; }
        else           { src = proj_w_raw; dst = wp; off = i - 49152; }
        float4 v = *(const float4*)(src + off);
        uint2 pk;
        pk.x = (unsigned int)f2bf(v.x) | ((unsigned int)f2bf(v.y) << 16);
        pk.y = (unsigned int)f2bf(v.z) | ((unsigned int)f2bf(v.w) << 16);
        *(uint2*)(dst + off) = pk;
    }
    {   // sums over this block's (b, i-slice): wave w == group w (c = tid>>2)
        int c = tid >> 2, qq = tid & 3;
        const float* xp = x + ((size_t)(b * 128 + c) << 12) + i0 + qq * 32;
        float s = 0.f, sq = 0.f;
#pragma unroll
        for (int k = 0; k < 8; ++k) {
            float4 v = *(const float4*)(xp + k * 4);
            s  += v.x + v.y + v.z + v.w;
            sq += v.x*v.x + v.y*v.y + v.z*v.z + v.w*v.w;
        }
#pragma unroll
        for (int m = 1; m < 64; m <<= 1) { s += __shfl_xor(s, m, 64); sq += __shfl_xor(sq, m, 64); }
        if (lane == 0) {
            sums[((b * 8 + wave) * 32 + tile) * 2]     = s;
            sums[((b * 8 + wave) * 32 + tile) * 2 + 1] = sq;
        }
    }
    grid.sync();                       // all sums + weights visible device-wide

    // ================= Phase 2: stats -> h -> Q/K/V GEMMs =================
    if (tid < 8) {                     // reduce 32 partials per group
        float s = 0.f, q = 0.f;
        const float* sp = sums + (size_t)((b * 8 + tid) * 32) * 2;
#pragma unroll
        for (int i = 0; i < 32; ++i) { s += sp[i * 2]; q += sp[i * 2 + 1]; }
        float mean = s * (1.f / 65536.f);
        float var  = q * (1.f / 65536.f) - mean * mean;
        ms[tid][0] = mean;
        ms[tid][1] = rsqrtf(var + 1e-5f);
    }
    __syncthreads();

    // h = GN(x) for rows i0..i0+127 -> O_lds[i_local][c]   (R25-verbatim)
    {
        int c = tid >> 2, qq = tid & 3;
        float mean = ms[c >> 4][0], rstd = ms[c >> 4][1];
        float ga = gn_w[c] * rstd;
        float be = gn_b[c] - mean * ga;
        const float* xp = x + ((size_t)(b * 128 + c) << 12) + i0 + qq * 32;
#pragma unroll
        for (int k = 0; k < 8; ++k) {
            float4 v = *(const float4*)(xp + k * 4);
            int il = qq * 32 + k * 4;
            O_lds[il + 0][c] = f2bf(v.x * ga + be);
            O_lds[il + 1][c] = f2bf(v.y * ga + be);
            O_lds[il + 2][c] = f2bf(v.z * ga + be);
            O_lds[il + 3][c] = f2bf(v.w * ga + be);
        }
    }
    __syncthreads();

    // Q GEMM -> Q_lds in K0/K1 (R25-verbatim): wave owns 16 o-rows
    {
        int o0q = wave * 16;
        short8 af[4];
#pragma unroll
        for (int ks = 0; ks < 4; ++ks)
            af[ks] = ldg8(wq + (size_t)(o0q + l15) * 128 + ks * 32 + q4 * 8);
        float qb[4];
#pragma unroll
        for (int r = 0; r < 4; ++r) qb[r] = qkv_b[o0q + q4 * 4 + r];
#pragma unroll
        for (int nt = 0; nt < 8; ++nt) {         // D[row=o(reg)][col=n=l15]
            f32x4 qacc = {0.f, 0.f, 0.f, 0.f};
#pragma unroll
            for (int ks = 0; ks < 4; ++ks) {
                short8 bf = *(const short8*)&O_lds[nt * 16 + l15][ks * 32 + q4 * 8];
                qacc = MFMA_BF16(af[ks], bf, qacc);
            }
            unsigned int lo = (unsigned int)f2bf((qacc[0] + qb[0]) * QSCALE) |
                              ((unsigned int)f2bf((qacc[1] + qb[1]) * QSCALE) << 16);
            unsigned int hi = (unsigned int)f2bf((qacc[2] + qb[2]) * QSCALE) |
                              ((unsigned int)f2bf((qacc[3] + qb[3]) * QSCALE) << 16);
            uint2 pk; pk.x = lo; pk.y = hi;
            unsigned short* qrow = (nt < 4) ? &K0[nt * 16 + l15][0]
                                            : &K1[(nt - 4) * 16 + l15][0];
            *(uint2*)(qrow + o0q + q4 * 4) = pk;
        }
    }
    // K GEMM -> k_ws (R24/25 k_qkv K pattern, 8 waves x 16 o-rows)
    {
        int o0 = wave * 16;
        short8 af[4];
#pragma unroll
        for (int ks = 0; ks < 4; ++ks)
            af[ks] = ldg8(wq + (size_t)(128 + o0 + l15) * 128 + ks * 32 + q4 * 8);
        float bias[4];
#pragma unroll
        for (int r = 0; r < 4; ++r) bias[r] = qkv_b[128 + o0 + q4 * 4 + r];
#pragma unroll
        for (int nt = 0; nt < 8; ++nt) {         // D[row=o(reg)][col=n=l15]
            f32x4 acc = {0.f, 0.f, 0.f, 0.f};
#pragma unroll
            for (int ks = 0; ks < 4; ++ks) {
                short8 bf = *(const short8*)&O_lds[nt * 16 + l15][ks * 32 + q4 * 8];
                acc = MFMA_BF16(af[ks], bf, acc);
            }
            int n = i0 + nt * 16 + l15;
            unsigned int lo = (unsigned int)f2bf(acc[0] + bias[0]) |
                              ((unsigned int)f2bf(acc[1] + bias[1]) << 16);
            unsigned int hi = (unsigned int)f2bf(acc[2] + bias[2]) |
                              ((unsigned int)f2bf(acc[3] + bias[3]) << 16);
            uint2 pk; pk.x = lo; pk.y = hi;
            *(uint2*)&k_ws[((size_t)(b * 4096 + n) << 7) + o0 + q4 * 4] = pk;
        }
    }
    // V GEMM (transposed) -> vstage in V0/V1: wave owns c = wave*16 + l15
    {
        int c = wave * 16 + l15;
        short8 af[4];
#pragma unroll
        for (int ks = 0; ks < 4; ++ks)
            af[ks] = ldg8(wq + (size_t)(256 + wave * 16 + l15) * 128 + ks * 32 + q4 * 8);
        float vb = qkv_b[256 + wave * 16 + l15];
        unsigned short* vrow = ((wave < 4) ? (unsigned short*)&V0[0][0]
                                           : (unsigned short*)&V1[0][0]) + (c & 63) * 128;
#pragma unroll
        for (int nt = 0; nt < 8; ++nt) {         // D[row=n(reg)][col=c=l15]
            f32x4 acc = {0.f, 0.f, 0.f, 0.f};
#pragma unroll
            for (int ks = 0; ks < 4; ++ks) {
                short8 bf = *(const short8*)&O_lds[nt * 16 + l15][ks * 32 + q4 * 8];
                acc = MFMA_BF16(bf, af[ks], acc);
            }
            unsigned int lo = (unsigned int)f2bf(acc[0] + vb) |
                              ((unsigned int)f2bf(acc[1] + vb) << 16);
            unsigned int hi = (unsigned int)f2bf(acc[2] + vb) |
                              ((unsigned int)f2bf(acc[3] + vb) << 16);
            uint2 pk; pk.x = lo; pk.y = hi;
            *(uint2*)&vrow[nt * 16 + q4 * 4] = pk;
        }
    }
    __syncthreads();                   // Q_lds + vstage complete

    // coalesced v_ws write: thread t -> c = t>>2, quarter q -> 64 B contig
    {
        int c = tid >> 2, qq = tid & 3;
        const unsigned short* src = ((c < 64) ? (const unsigned short*)&V0[0][0]
                                              : (const unsigned short*)&V1[0][0]) +
                                    (c & 63) * 128 + qq * 32;
        unsigned short* dst = v_ws + ((size_t)(b * 128 + c) << 12) + i0 + qq * 32;
        uint4 a0 = *(const uint4*)(src + 0);
        uint4 a1 = *(const uint4*)(src + 8);
        uint4 a2 = *(const uint4*)(src + 16);
        uint4 a3 = *(const uint4*)(src + 24);
        *(uint4*)(dst + 0)  = a0;
        *(uint4*)(dst + 8)  = a1;
        *(uint4*)(dst + 16) = a2;
        *(uint4*)(dst + 24) = a3;
    }
    // qf from Q_lds (R25-verbatim)
    short8 qf[8];
    {
        const unsigned short* qrow = (ih < 2) ? &K0[irow][0] : &K1[irow - 64][0];
#pragma unroll
        for (int ks = 0; ks < 8; ++ks)
            qf[ks] = *(const short8*)(qrow + ks * 16 + h * 8);
    }
    __syncthreads();                   // qf + vstage reads done; LDS free for staging
    grid.sync();                       // all blocks' k_ws/v_ws visible device-wide

    // ================= Phase 3: flash attention + proj (R25-verbatim) ==============
    f32x16 acc[4];                           // O[i(reg)][c = ct*32 + l31], FULL C
#pragma unroll
    for (int ct = 0; ct < 4; ++ct)
#pragma unroll
        for (int e = 0; e < 16; ++e) acc[ct][e] = 0.f;
    float l_run = 0.f;

    const unsigned short* kbase = k_ws + ((size_t)b << 19);
    int ksrc[2];
#pragma unroll
    for (int q = 0; q < 2; ++q) {
        int c   = q * 512 + tid;
        int row = c >> 4;
        ksrc[q] = row * 16 + ((c & 15) ^ (row & 15));
    }
    const unsigned short* vlane = v_ws + ((size_t)b << 19) +
        ((size_t)(tid >> 3) << 12) +
        ((((tid & 7) ^ ((tid >> 3) & 7) ^ wave)) << 3);

#define STAGE(T, KD, VD)                                                              \
  do {                                                                                \
    _Pragma("unroll")                                                                 \
    for (int q = 0; q < 2; ++q)                                                       \
      gload16(kbase + (size_t)(T) * 8192 + ksrc[q] * 8,                               \
              (char*)(&KD[0][0]) + q * 8192 + wave * 1024);                           \
    _Pragma("unroll")                                                                 \
    for (int q = 0; q < 2; ++q)                                                       \
      gload16(vlane + (size_t)q * 262144 + (T) * 64,                                  \
              (char*)(&VD[0][0]) + q * 8192 + wave * 1024);                           \
  } while (0)

#define BAR_A()                                                                       \
  do {                                                                                \
    asm volatile("s_waitcnt vmcnt(0)" ::: "memory");                                  \
    __builtin_amdgcn_s_barrier();                                                     \
    __builtin_amdgcn_sched_barrier(0);                                                \
  } while (0)

    const int krow = jh * 32 + l31;
    const int ksw  = l31 & 15;
    const int vk   = (l31 & 7) ^ (l31 >> 3);

    STAGE(0, K0, V0);

#define ATTN_ITER(IT, KR, VR, KP, VP)                                                 \
  do {                                                                                \
    BAR_A();                                                                          \
    if ((IT) < 63) STAGE((IT) + 1, KP, VP);                                           \
    f32x16 s;                                                                         \
    _Pragma("unroll")                                                                 \
    for (int e = 0; e < 16; ++e) s[e] = 0.f;                                          \
    _Pragma("unroll")                                                                 \
    for (int ks = 0; ks < 8; ++ks) {                                                  \
      short8 kf = *(const short8*)&KR[krow][((ks * 2 + h) ^ ksw) << 3];               \
      s = MFMA32(kf, qf[ks], s);                                                      \
    }                                                                                 \
    float pvv[16];                                                                    \
    _Pragma("unroll")                                                                 \
    for (int e = 0; e < 16; ++e) pvv[e] = EXP2(fminf(s[e], 30.f));                    \
    l_run += (((pvv[0] + pvv[1]) + (pvv[2] + pvv[3])) +                               \
              ((pvv[4] + pvv[5]) + (pvv[6] + pvv[7]))) +                              \
             (((pvv[8] + pvv[9]) + (pvv[10] + pvv[11])) +                             \
              ((pvv[12] + pvv[13]) + (pvv[14] + pvv[15])));                           \
    short8 paf[2];                                                                    \
    _Pragma("unroll")                                                                 \
    for (int ks = 0; ks < 2; ++ks) {                                                  \
      const float* pp = pvv + ks * 8;                                                 \
      unsigned int Wa = cvtpk(pp[0], pp[1]);                                          \
      unsigned int Wc = cvtpk(pp[2], pp[3]);                                          \
      unsigned int Wb = cvtpk(pp[4], pp[5]);                                          \
      unsigned int Wd = cvtpk(pp[6], pp[7]);                                          \
      auto r1 = __builtin_amdgcn_permlane32_swap(Wa, Wb, false, false);               \
      auto r2 = __builtin_amdgcn_permlane32_swap(Wc, Wd, false, false);               \
      uint4 aw; aw.x = r1[0]; aw.y = r2[0]; aw.z = r1[1]; aw.w = r2[1];               \
      paf[ks] = __builtin_bit_cast(short8, aw);                                       \
    }                                                                                 \
    _Pragma("unroll")                                                                 \
    for (int ks = 0; ks < 2; ++ks)                                                    \
      _Pragma("unroll")                                                               \
      for (int ct = 0; ct < 4; ++ct) {                                                \
        short8 vf = *(const short8*)&VR[ct * 32 + l31]                                \
            [((jh * 4 + ks * 2 + h) ^ vk ^ ((ct & 1) << 2)) << 3];                    \
        acc[ct] = MFMA32(paf[ks], vf, acc[ct]);                                       \
      }                                                                               \
  } while (0)

    for (int ib = 0; ib < 32; ++ib) {
        int it = ib * 2;
        ATTN_ITER(it,     K0, V0, K1, V1);
        ATTN_ITER(it + 1, K1, V1, K0, V0);
    }
#undef ATTN_ITER
#undef STAGE
#undef BAR_A

    // ---- epilogue 1: jh-pair O reduce (overlay deposit in K/V bufs, f32) ----
    __syncthreads();
    float l2 = l_run + __shfl_xor(l_run, 32);
    if (h == 0) Lp[jh * 128 + irow] = l2;
    float* ObLow  = (ih < 2) ? (float*)&K0[0][0] : (float*)&K1[0][0];
    float* ObHigh = (ih < 2) ? (float*)&V0[0][0] : (float*)&V1[0][0];
    const int vbase = (ih & 1) * 32;
    if (jh) {
#pragma unroll
        for (int cc = 0; cc < 2; ++cc)
#pragma unroll
            for (int r = 0; r < 16; ++r) {
                int il = (r & 3) + ((r >> 2) << 3) + (h << 2);
                ObLow[(vbase + il) * 64 + cc * 32 + l31] = (cc == 0) ? acc[0][r] : acc[1][r];
            }
    } else {
#pragma unroll
        for (int cc = 0; cc < 2; ++cc)
#pragma unroll
            for (int r = 0; r < 16; ++r) {
                int il = (r & 3) + ((r >> 2) << 3) + (h << 2);
                ObHigh[(vbase + il) * 64 + cc * 32 + l31] = (cc == 0) ? acc[2][r] : acc[3][r];
            }
    }
    __syncthreads();
    // ---- epilogue 2: normalize + write bf16 O to O_lds ----
    {
        float rl[16];
#pragma unroll
        for (int r = 0; r < 16; ++r) {
            int il = (r & 3) + ((r >> 2) << 3) + (h << 2);
            rl[r] = 1.0f / (Lp[ih * 32 + il] + Lp[128 + ih * 32 + il]);
        }
        if (jh) {
#pragma unroll
            for (int cc = 0; cc < 2; ++cc)
#pragma unroll
                for (int r = 0; r < 16; ++r) {
                    int il = (r & 3) + ((r >> 2) << 3) + (h << 2);
                    float own = (cc == 0) ? acc[2][r] : acc[3][r];
                    float v = own + ObHigh[(vbase + il) * 64 + cc * 32 + l31];
                    O_lds[ih * 32 + il][64 + cc * 32 + l31] = f2bf(v * rl[r]);
                }
        } else {
#pragma unroll
            for (int cc = 0; cc < 2; ++cc)
#pragma unroll
                for (int r = 0; r < 16; ++r) {
                    int il = (r & 3) + ((r >> 2) << 3) + (h << 2);
                    float own = (cc == 0) ? acc[0][r] : acc[1][r];
                    float v = own + ObLow[(vbase + il) * 64 + cc * 32 + l31];
                    O_lds[ih * 32 + il][cc * 32 + l31] = f2bf(v * rl[r]);
                }
        }
    }
    __syncthreads();

    // ---- epilogue 3: proj GEMM + bias + residual ----
    {
        int o0 = wave * 16;
        short8 af[4];
#pragma unroll
        for (int ks = 0; ks < 4; ++ks)
            af[ks] = ldg8(wp + (size_t)(o0 + l15) * 128 + ks * 32 + q4 * 8);
        float pb[4];
#pragma unroll
        for (int r = 0; r < 4; ++r) pb[r] = proj_b[o0 + q4 * 4 + r];

#pragma unroll
        for (int nt = 0; nt < 8; ++nt) {
            f32x4 pacc = {0.f, 0.f, 0.f, 0.f};
#pragma unroll
            for (int ks = 0; ks < 4; ++ks) {
                short8 bf = *(const short8*)&O_lds[nt * 16 + l15][ks * 32 + q4 * 8];
                pacc = MFMA_BF16(af[ks], bf, pacc);
            }
#pragma unroll
            for (int r = 0; r < 4; ++r) {
                size_t idx = ((size_t)(b * 128 + o0 + q4 * 4 + r) << 12) +
                             i0 + nt * 16 + l15;
                out[idx] = x[idx] + pacc[r] + pb[r];
            }
        }
    }
}

// ---------------- launch ----------------
extern "C" void kernel_launch(void* const* d_in, const int* in_sizes, int n_in,
                              void* d_out, int out_size, void* d_ws, size_t ws_size,
                              hipStream_t stream) {
    const float* x      = (const float*)d_in[0];
    const float* gn_w   = (const float*)d_in[1];
    const float* gn_b   = (const float*)d_in[2];
    const float* qkv_w  = (const float*)d_in[3];
    const float* qkv_b  = (const float*)d_in[4];
    const float* proj_w = (const float*)d_in[5];
    const float* proj_b = (const float*)d_in[6];
    float* out = (float*)d_out;

    char* ws = (char*)d_ws;
    float* sums           = (float*)ws;                              // 16 KB partials (no init)
    unsigned short* wq    = (unsigned short*)(ws + 16384);           // 96 KB (Wq|Wk|Wv)
    unsigned short* wp    = (unsigned short*)(ws + 16384 + 98304);   // 32 KB
    unsigned short* k_ws  = (unsigned short*)(ws + ((size_t)1 << 20));   // 8 MB
    unsigned short* v_ws  = (unsigned short*)(ws + ((size_t)9 << 20));   // 8 MB

    void* args[] = { (void*)&x, (void*)&sums, (void*)&qkv_w, (void*)&proj_w,
                     (void*)&wq, (void*)&wp, (void*)&gn_w, (void*)&gn_b,
                     (void*)&qkv_b, (void*)&k_ws, (void*)&v_ws,
                     (void*)&proj_b, (void*)&out };
    hipLaunchCooperativeKernel((void*)k_fused, dim3(256), dim3(512),
                               args, 0, stream);
}